// Round 4
// baseline (198.990 us; speedup 1.0000x reference)
//
#include <hip/hip_runtime.h>
#include <hip/hip_fp16.h>
#include <math.h>
#include <stdint.h>

#define N_NODES 100000
#define N_EDGES 1600000
#define N_TOT   (N_EDGES + N_NODES)   // edges + self-loops
#define NEG_SLOPE 0.2f
#define LOG2E 1.44269504088896340736f

#define CB     128                            // dst nodes per bucket
#define CBBITS 7
#define NCB    ((N_NODES + CB - 1) / CB)      // 782 buckets
#define TP     2048                           // edges per partition block
#define NPB    ((N_EDGES + TP - 1) / TP)      // 782 partition blocks
#define WINB   2560                           // fixed ssrc window per bucket (mean load 2174, +11 sigma)

typedef int nt_int4 __attribute__((ext_vector_type(4)));

// ---------------- layer 1: node transform -------------------------------
// Key refactor (R3): layer-1 aggregation is linear in x (h1 = x*W1), so
// k_gather1 gathers 16-B fp16 x-rows instead of 128-B h1 rows and applies
// W1 AFTER aggregation. Working set (xh 1.6MB + as1h 1.6MB) fits per-XCD
// L2. k_node1 only produces as/ad (attention logits, pre-scaled by log2e
// for raw v_exp_f32) and the padded fp16 x rows — no h1h table.
__global__ void k_node1(const float* __restrict__ x, const float* __restrict__ W1,
                        const float* __restrict__ a_src1, const float* __restrict__ a_dst1,
                        __half* __restrict__ xh, __half* __restrict__ as1h,
                        float* __restrict__ ad1) {
    int tid  = blockIdx.x * blockDim.x + threadIdx.x;
    int n    = tid >> 3;
    int head = tid & 7;
    if (n >= N_NODES) return;

    float xv[5];
#pragma unroll
    for (int k = 0; k < 5; ++k) xv[k] = x[n * 5 + k];

    float as = 0.f, ad = 0.f;
#pragma unroll
    for (int j = 0; j < 8; ++j) {
        int c = head * 8 + j;
        float acc = 0.f;
#pragma unroll
        for (int k = 0; k < 5; ++k) acc += xv[k] * W1[k * 64 + c];
        as += acc * a_src1[c];
        ad += acc * a_dst1[c];
    }
    as1h[n * 8 + head] = __float2half(as * LOG2E);
    ad1[n * 8 + head] = ad * LOG2E;

    if (head == 0) {                    // padded fp16 x row: 8 halves = 16 B
        __half2 p0 = __halves2half2(__float2half(xv[0]), __float2half(xv[1]));
        __half2 p1 = __halves2half2(__float2half(xv[2]), __float2half(xv[3]));
        __half2 p2 = __halves2half2(__float2half(xv[4]), __float2half(0.f));
        __half2 p3 = __halves2half2(__float2half(0.f), __float2half(0.f));
        __half2* xp = (__half2*)&xh[(size_t)n * 8];
        xp[0] = p0; xp[1] = p1; xp[2] = p2; xp[3] = p3;
    }
}

// ---------------- block-radix partition (782 blocks x 512 thr) ----------
__global__ void __launch_bounds__(512) k_part(
        const int* __restrict__ src, const int* __restrict__ dst,
        int* __restrict__ ofs, unsigned* __restrict__ pairs) {
    __shared__ int lcnt[1024];           // bins (782 used), then cursors
    __shared__ int sm[512];
    __shared__ unsigned stage[TP];       // 8 KB
    int blk = blockIdx.x;
    int t = threadIdx.x;
    int base = blk * TP + t * 4;
    bool act = base < N_EDGES;           // tail block: exact multiple of 4
    int nE = min(TP, N_EDGES - blk * TP);

    lcnt[t] = 0; lcnt[t + 512] = 0;
    __syncthreads();

    nt_int4 s4, d4;
    if (act) {
        s4 = __builtin_nontemporal_load((const nt_int4*)(src + base));
        d4 = __builtin_nontemporal_load((const nt_int4*)(dst + base));
#pragma unroll
        for (int j = 0; j < 4; ++j) atomicAdd(&lcnt[d4[j] >> CBBITS], 1);
    }
    __syncthreads();

    // exclusive scan over 1024 bins, 2/thread
    int b0 = lcnt[t * 2], b1 = lcnt[t * 2 + 1];
    int local = b0 + b1;
    sm[t] = local;
    __syncthreads();
    for (int off = 1; off < 512; off <<= 1) {
        int u = (t >= off) ? sm[t - off] : 0;
        __syncthreads();
        sm[t] += u;
        __syncthreads();
    }
    int run = sm[t] - local;
    lcnt[t * 2] = run; lcnt[t * 2 + 1] = run + b0;
    int* orow = ofs + (size_t)blk * (NCB + 1);
    if (t * 2     <= NCB) orow[t * 2]     = run;
    if (t * 2 + 1 <= NCB) orow[t * 2 + 1] = run + b0;
    __syncthreads();

    if (act) {
#pragma unroll
        for (int j = 0; j < 4; ++j) {
            int d = d4[j], s = s4[j];
            int bin = d >> CBBITS;
            int idx = atomicAdd(&lcnt[bin], 1);
            stage[idx] = ((unsigned)(d & (CB - 1)) << 17) | (unsigned)s;
        }
    }
    __syncthreads();
    for (int i = t; i < nE; i += 512)
        pairs[(size_t)blk * TP + i] = stage[i];      // coalesced dump
}

// ---------------- bucket-local CSR build, single-pass (782 x 512) -------
__global__ void __launch_bounds__(512) k_csr(
        const int* __restrict__ ofs, const unsigned* __restrict__ pairs,
        int* __restrict__ rbeg, int* __restrict__ rend, int* __restrict__ ssrc) {
    __shared__ unsigned stIn[WINB];      // 10.25 KB
    __shared__ int stOut[WINB];          // 10.25 KB
    __shared__ int lcnt[CB], lofs[CB], lcur[CB];
    __shared__ int wsum[2];
    __shared__ int acur;
    int B = blockIdx.x, t = threadIdx.x;
    int nvalid = min(CB, N_NODES - B * CB);
    int obase = B * WINB;

    if (t < CB) {
        lcnt[t] = (t < nvalid) ? 1 : 0;   // self-loop pre-count
        lcur[t] = 1;                      // slot 0 = self-loop
    }
    if (t == 0) acur = 0;
    __syncthreads();

    // single pass: append records to stIn + histogram
    for (int blk = t; blk < NPB; blk += 512) {
        int o0 = ofs[(size_t)blk * (NCB + 1) + B];
        int o1 = ofs[(size_t)blk * (NCB + 1) + B + 1];
        int n = o1 - o0;
        if (n > 0) {
            int p = atomicAdd(&acur, n);
            const unsigned* pp = pairs + (size_t)blk * TP + o0;
            for (int i = 0; i < n; ++i) {
                unsigned r = pp[i];
                stIn[p + i] = r;
                atomicAdd(&lcnt[r >> 17], 1);
            }
        }
    }
    __syncthreads();
    int m = acur;

    // exclusive scan over 128 bins (first 2 waves carry data)
    int v = (t < CB) ? lcnt[t] : 0;
    int ln = t & 63, wv = t >> 6;
    int sc = v;
#pragma unroll
    for (int off = 1; off < 64; off <<= 1) {
        int u = __shfl_up(sc, off, 64);
        if (ln >= off) sc += u;
    }
    if (ln == 63 && wv < 2) wsum[wv] = sc;
    __syncthreads();
    int wbase = (wv == 1) ? wsum[0] : 0;
    int ex = wbase + sc - v;
    if (t < CB) {
        lofs[t] = ex;
        int gi = B * CB + t;
        if (gi < N_NODES) {
            rbeg[gi] = obase + ex;
            rend[gi] = obase + ex + v;
            stOut[ex] = gi;               // self-loop record, slot 0
        }
    }
    __syncthreads();

    // scatter into final CSR order (LDS -> LDS)
    for (int k = t; k < m; k += 512) {
        unsigned p = stIn[k];
        int dl = p >> 17;
        int idx = atomicAdd(&lcur[dl], 1);
        stOut[lofs[dl] + idx] = (int)(p & 0x1FFFF);
    }
    __syncthreads();

    // coalesced dump
    int tot = m + nvalid;
    for (int i = t; i < tot; i += 512) ssrc[obase + i] = stOut[i];
}

// ---------------- layer 1 gather + softmax + ELU + fused node2 ----------
// One wave per dst. lane = (edge-slot e = lane>>3, head h = lane&7).
// Gathers 16-B fp16 x rows (L2-resident, 1.6 MB) + as1h (1.6 MB); applies
// W1 in fp32 to the per-head alpha-weighted x-sum in the epilogue.
__global__ void __launch_bounds__(256) k_gather1(
        const int* __restrict__ rbeg, const int* __restrict__ rend,
        const int* __restrict__ ssrc, const float4* __restrict__ xh4,
        const __half* __restrict__ as1h, const float* __restrict__ ad1,
        const float* __restrict__ b1, const float* __restrict__ W1,
        const float* __restrict__ W2,
        const float* __restrict__ a_src2, const float* __restrict__ a_dst2,
        float4* __restrict__ rec) {
    int gtid = blockIdx.x * blockDim.x + threadIdx.x;
    int d    = gtid >> 6;
    int lane = threadIdx.x & 63;
    if (d >= N_NODES) return;
    int e = lane >> 3;         // edge slot within group (0..7)
    int h = lane & 7;          // head

    int beg = rbeg[d], end = rend[d];
    float adv = ad1[d * 8 + h];                // pre-scaled by log2e
    float c0 = 0.f, c1 = 0.f, c2 = 0.f, c3 = 0.f, c4 = 0.f, den = 0.f;

    int k = beg;
    for (; k + 16 <= end; k += 16) {           // 2 independent 8-edge groups
        int sA = ssrc[k + e];
        int sB = ssrc[k + 8 + e];
        float eA = __half2float(as1h[sA * 8 + h]);
        float eB = __half2float(as1h[sB * 8 + h]);
        float4 xA = xh4[sA];                   // 8 halves: x0..x4,pad
        float4 xB = xh4[sB];
        float tA = eA + adv; tA = fmaxf(tA, NEG_SLOPE * tA);
        float tB = eB + adv; tB = fmaxf(tB, NEG_SLOPE * tB);
        float wA = __builtin_amdgcn_exp2f(tA);
        float wB = __builtin_amdgcn_exp2f(tB);
        float2 A01 = __half22float2(*(__half2*)&xA.x);
        float2 A23 = __half22float2(*(__half2*)&xA.y);
        float2 A4_ = __half22float2(*(__half2*)&xA.z);
        float2 B01 = __half22float2(*(__half2*)&xB.x);
        float2 B23 = __half22float2(*(__half2*)&xB.y);
        float2 B4_ = __half22float2(*(__half2*)&xB.z);
        c0 += wA * A01.x + wB * B01.x;
        c1 += wA * A01.y + wB * B01.y;
        c2 += wA * A23.x + wB * B23.x;
        c3 += wA * A23.y + wB * B23.y;
        c4 += wA * A4_.x + wB * B4_.x;
        den += wA + wB;
    }
    for (; k < end; k += 8) {                  // masked 8-edge tail groups
        int ki = k + e;
        bool val = ki < end;
        int s = ssrc[val ? ki : beg];
        float ev = __half2float(as1h[s * 8 + h]);
        float4 xr = xh4[s];
        float t = ev + adv; t = fmaxf(t, NEG_SLOPE * t);
        float w = val ? __builtin_amdgcn_exp2f(t) : 0.f;
        float2 X01 = __half22float2(*(__half2*)&xr.x);
        float2 X23 = __half22float2(*(__half2*)&xr.y);
        float2 X4_ = __half22float2(*(__half2*)&xr.z);
        c0 += w * X01.x; c1 += w * X01.y;
        c2 += w * X23.x; c3 += w * X23.y;
        c4 += w * X4_.x;
        den += w;
    }

    // reduce across the 8 edge slots (lanes xor 8,16,32)
#define RED8(x) x += __shfl_xor(x, 8, 64); x += __shfl_xor(x, 16, 64); x += __shfl_xor(x, 32, 64);
    RED8(c0) RED8(c1) RED8(c2) RED8(c3) RED8(c4) RED8(den)
#undef RED8

    float inv = 1.f / den;                     // den>0 (self-loop guarantees)
    float s0 = c0 * inv, s1 = c1 * inv, s2 = c2 * inv,
          s3 = c3 * inv, s4 = c4 * inv;       // alpha-weighted mean x row

    // h = (sum alpha x) * W1 + b1  — this head's 8 channels, fp32
    float4 hA = ((const float4*)b1)[2 * h];
    float4 hB = ((const float4*)b1)[2 * h + 1];
#pragma unroll
    for (int c = 0; c < 5; ++c) {
        float xc = (c == 0) ? s0 : (c == 1) ? s1 : (c == 2) ? s2
                 : (c == 3) ? s3 : s4;
        float4 wA = *(const float4*)(W1 + c * 64 + 8 * h);
        float4 wB = *(const float4*)(W1 + c * 64 + 8 * h + 4);
        hA.x += xc * wA.x; hA.y += xc * wA.y; hA.z += xc * wA.z; hA.w += xc * wA.w;
        hB.x += xc * wB.x; hB.y += xc * wB.y; hB.z += xc * wB.z; hB.w += xc * wB.w;
    }
    float v0 = hA.x, v1 = hA.y, v2 = hA.z, v3 = hA.w;
    float v4 = hB.x, v5 = hB.y, v6 = hB.z, v7 = hB.w;
    v0 = (v0 > 0.f) ? v0 : (__expf(v0) - 1.f); // ELU
    v1 = (v1 > 0.f) ? v1 : (__expf(v1) - 1.f);
    v2 = (v2 > 0.f) ? v2 : (__expf(v2) - 1.f);
    v3 = (v3 > 0.f) ? v3 : (__expf(v3) - 1.f);
    v4 = (v4 > 0.f) ? v4 : (__expf(v4) - 1.f);
    v5 = (v5 > 0.f) ? v5 : (__expf(v5) - 1.f);
    v6 = (v6 > 0.f) ? v6 : (__expf(v6) - 1.f);
    v7 = (v7 > 0.f) ? v7 : (__expf(v7) - 1.f);

    // fused layer-2 transform: this lane's 8 channels (head h) x W2[64,2]
    const float4* w4 = (const float4*)(W2 + h * 16);
    float4 wq0 = w4[0], wq1 = w4[1], wq2 = w4[2], wq3 = w4[3];
    float h20 = v0 * wq0.x + v1 * wq0.z + v2 * wq1.x + v3 * wq1.z
              + v4 * wq2.x + v5 * wq2.z + v6 * wq3.x + v7 * wq3.z;
    float h21 = v0 * wq0.y + v1 * wq0.w + v2 * wq1.y + v3 * wq1.w
              + v4 * wq2.y + v5 * wq2.w + v6 * wq3.y + v7 * wq3.w;
    // reduce across the 8 heads (lanes xor 1,2,4)
    h20 += __shfl_xor(h20, 1, 64); h20 += __shfl_xor(h20, 2, 64); h20 += __shfl_xor(h20, 4, 64);
    h21 += __shfl_xor(h21, 1, 64); h21 += __shfl_xor(h21, 2, 64); h21 += __shfl_xor(h21, 4, 64);

    if (lane == 0) {
        float as2v = h20 * a_src2[0] + h21 * a_src2[1];
        float ad2v = h20 * a_dst2[0] + h21 * a_dst2[1];
        rec[d] = make_float4(h20, h21, as2v, ad2v);
    }
}

// ---------------- layer 2: per-dst gather + log_softmax -----------------
__global__ void k_gather2(const int* __restrict__ rbeg, const int* __restrict__ rend,
                          const int* __restrict__ ssrc, const float4* __restrict__ rec,
                          const float* __restrict__ b2, float* __restrict__ out) {
    int gtid = blockIdx.x * blockDim.x + threadIdx.x;
    int d    = gtid >> 4;
    int lane = gtid & 15;
    if (d >= N_NODES) return;

    int beg = rbeg[d], end = rend[d];
    float adv = rec[d].w;
    float n0 = 0.f, n1 = 0.f, den = 0.f;
    int k = beg + lane;
    for (; k + 16 < end; k += 32) {
        int s0 = ssrc[k], s1 = ssrc[k + 16];
        float4 r0 = rec[s0];
        float4 r1 = rec[s1];
        float t0 = r0.z + adv; t0 = fmaxf(t0, NEG_SLOPE * t0);
        float t1 = r1.z + adv; t1 = fmaxf(t1, NEG_SLOPE * t1);
        float w0 = __expf(t0), w1 = __expf(t1);
        n0 += w0 * r0.x + w1 * r1.x;
        n1 += w0 * r0.y + w1 * r1.y;
        den += w0 + w1;
    }
    if (k < end) {
        int s = ssrc[k];
        float4 r = rec[s];
        float t = r.z + adv; t = fmaxf(t, NEG_SLOPE * t);
        float w = __expf(t);
        n0 += w * r.x; n1 += w * r.y; den += w;
    }
#pragma unroll
    for (int off = 8; off; off >>= 1) {
        n0  += __shfl_xor(n0,  off, 16);
        n1  += __shfl_xor(n1,  off, 16);
        den += __shfl_xor(den, off, 16);
    }
    if (lane == 0) {
        float o0 = n0 / den + b2[0];
        float o1 = n1 / den + b2[1];
        float m  = fmaxf(o0, o1);
        float lse = m + __logf(__expf(o0 - m) + __expf(o1 - m));
        out[d * 2 + 0] = o0 - lse;
        out[d * 2 + 1] = o1 - lse;
    }
}

extern "C" void kernel_launch(void* const* d_in, const int* in_sizes, int n_in,
                              void* d_out, int out_size, void* d_ws, size_t ws_size,
                              hipStream_t stream) {
    const float* x      = (const float*)d_in[0];
    const int*   ei     = (const int*)d_in[1];     // [2, E] int32
    const float* W1     = (const float*)d_in[2];
    const float* a_src1 = (const float*)d_in[3];
    const float* a_dst1 = (const float*)d_in[4];
    const float* b1     = (const float*)d_in[5];
    const float* W2     = (const float*)d_in[6];
    const float* a_src2 = (const float*)d_in[7];
    const float* a_dst2 = (const float*)d_in[8];
    const float* b2     = (const float*)d_in[9];
    float* out = (float*)d_out;

    const int* src = ei;
    const int* dst = ei + N_EDGES;

    // ---- workspace layout (~26 MB), everything written before read:
    // no memset needed.
    int* ofs    = (int*)d_ws;                                   // NPB*(NCB+1) (2.45 MB)
    int* rbeg   = ofs + (size_t)NPB * (NCB + 1);                // N
    int* rend   = rbeg + N_NODES;                               // N
    unsigned* pairs = (unsigned*)(rend + N_NODES);              // E (6.4 MB)
    int* ssrc   = (int*)(pairs + N_EDGES);                      // NCB*WINB (8 MB)
    uintptr_t pp = ((uintptr_t)(ssrc + (size_t)NCB * WINB) + 255) & ~(uintptr_t)255;
    float4*   rec  = (float4*)pp;                               // N float4
    float*    ad1  = (float*)(rec + N_NODES);                   // N*8 fp32
    __half*   as1h = (__half*)(ad1 + (size_t)N_NODES * 8);      // N*8 fp16
    __half*   xh   = as1h + (size_t)N_NODES * 8;                // N*8 fp16 (padded x rows)

    k_node1<<<(N_NODES * 8 + 255) / 256, 256, 0, stream>>>(x, W1, a_src1, a_dst1,
                                                           xh, as1h, ad1);
    k_part<<<NPB, 512, 0, stream>>>(src, dst, ofs, pairs);
    k_csr<<<NCB, 512, 0, stream>>>(ofs, pairs, rbeg, rend, ssrc);
    k_gather1<<<(N_NODES * 64 + 255) / 256, 256, 0, stream>>>(rbeg, rend, ssrc,
                                                              (const float4*)xh,
                                                              as1h, ad1, b1, W1, W2,
                                                              a_src2, a_dst2, rec);
    k_gather2<<<(N_NODES * 16 + 255) / 256, 256, 0, stream>>>(rbeg, rend, ssrc,
                                                              rec, b2, out);
}

// Round 5
// 174.267 us; speedup vs baseline: 1.1419x; 1.1419x over previous
//
#include <hip/hip_runtime.h>
#include <hip/hip_fp16.h>
#include <math.h>
#include <stdint.h>

#define N_NODES 100000
#define N_EDGES 1600000
#define N_TOT   (N_EDGES + N_NODES)   // edges + self-loops
#define NEG_SLOPE 0.2f
#define LOG2E 1.44269504088896340736f

#define CB     128                            // dst nodes per bucket
#define CBBITS 7
#define NCB    ((N_NODES + CB - 1) / CB)      // 782 buckets
#define TP     2048                           // edges per partition block
#define NPB    ((N_EDGES + TP - 1) / TP)      // 782 partition blocks
#define WINB   2560                           // fixed ssrc window per bucket (mean load 2174, +11 sigma)

typedef int nt_int4 __attribute__((ext_vector_type(4)));

// ---------------- layer 1: node transform -------------------------------
// Layer-1 aggregation is linear in x (h1 = x*W1): k_gather1 gathers 16-B
// fp16 x-rows and applies W1 AFTER aggregation. Working set (xh 1.6MB +
// as1h 1.6MB) fits per-XCD L2. as/ad logits pre-scaled by log2e for raw
// v_exp_f32.
__global__ void k_node1(const float* __restrict__ x, const float* __restrict__ W1,
                        const float* __restrict__ a_src1, const float* __restrict__ a_dst1,
                        __half* __restrict__ xh, __half* __restrict__ as1h,
                        float* __restrict__ ad1) {
    int tid  = blockIdx.x * blockDim.x + threadIdx.x;
    int n    = tid >> 3;
    int head = tid & 7;
    if (n >= N_NODES) return;

    float xv[5];
#pragma unroll
    for (int k = 0; k < 5; ++k) xv[k] = x[n * 5 + k];

    float as = 0.f, ad = 0.f;
#pragma unroll
    for (int j = 0; j < 8; ++j) {
        int c = head * 8 + j;
        float acc = 0.f;
#pragma unroll
        for (int k = 0; k < 5; ++k) acc += xv[k] * W1[k * 64 + c];
        as += acc * a_src1[c];
        ad += acc * a_dst1[c];
    }
    as1h[n * 8 + head] = __float2half(as * LOG2E);
    ad1[n * 8 + head] = ad * LOG2E;

    if (head == 0) {                    // padded fp16 x row: 8 halves = 16 B
        __half2 p0 = __halves2half2(__float2half(xv[0]), __float2half(xv[1]));
        __half2 p1 = __halves2half2(__float2half(xv[2]), __float2half(xv[3]));
        __half2 p2 = __halves2half2(__float2half(xv[4]), __float2half(0.f));
        __half2 p3 = __halves2half2(__float2half(0.f), __float2half(0.f));
        __half2* xp = (__half2*)&xh[(size_t)n * 8];
        xp[0] = p0; xp[1] = p1; xp[2] = p2; xp[3] = p3;
    }
}

// ---------------- block-radix partition (782 blocks x 512 thr) ----------
// ofs is TRANSPOSED: ofsT[bin * NPB + blk] so k_csr's per-bucket column
// reads are unit-stride coalesced. k_part's prefix writes become
// scattered (stride NPB*4) — stores don't stall the pipeline.
__global__ void __launch_bounds__(512) k_part(
        const int* __restrict__ src, const int* __restrict__ dst,
        int* __restrict__ ofsT, unsigned* __restrict__ pairs) {
    __shared__ int lcnt[1024];           // bins (782 used), then cursors
    __shared__ int sm[512];
    __shared__ unsigned stage[TP];       // 8 KB
    int blk = blockIdx.x;
    int t = threadIdx.x;
    int base = blk * TP + t * 4;
    bool act = base < N_EDGES;           // tail block: exact multiple of 4
    int nE = min(TP, N_EDGES - blk * TP);

    lcnt[t] = 0; lcnt[t + 512] = 0;
    __syncthreads();

    nt_int4 s4, d4;
    if (act) {
        s4 = __builtin_nontemporal_load((const nt_int4*)(src + base));
        d4 = __builtin_nontemporal_load((const nt_int4*)(dst + base));
#pragma unroll
        for (int j = 0; j < 4; ++j) atomicAdd(&lcnt[d4[j] >> CBBITS], 1);
    }
    __syncthreads();

    // exclusive scan over 1024 bins, 2/thread
    int b0 = lcnt[t * 2], b1 = lcnt[t * 2 + 1];
    int local = b0 + b1;
    sm[t] = local;
    __syncthreads();
    for (int off = 1; off < 512; off <<= 1) {
        int u = (t >= off) ? sm[t - off] : 0;
        __syncthreads();
        sm[t] += u;
        __syncthreads();
    }
    int run = sm[t] - local;
    lcnt[t * 2] = run; lcnt[t * 2 + 1] = run + b0;
    if (t * 2     <= NCB) ofsT[(size_t)(t * 2)     * NPB + blk] = run;
    if (t * 2 + 1 <= NCB) ofsT[(size_t)(t * 2 + 1) * NPB + blk] = run + b0;
    __syncthreads();

    if (act) {
#pragma unroll
        for (int j = 0; j < 4; ++j) {
            int d = d4[j], s = s4[j];
            int bin = d >> CBBITS;
            int idx = atomicAdd(&lcnt[bin], 1);
            stage[idx] = ((unsigned)(d & (CB - 1)) << 17) | (unsigned)s;
        }
    }
    __syncthreads();
    for (int i = t; i < nE; i += 512)
        pairs[(size_t)blk * TP + i] = stage[i];      // coalesced dump
}

// ---------------- bucket-local CSR build, single-pass (782 x 512) -------
__global__ void __launch_bounds__(512) k_csr(
        const int* __restrict__ ofsT, const unsigned* __restrict__ pairs,
        int* __restrict__ rbeg, int* __restrict__ rend, int* __restrict__ ssrc) {
    __shared__ unsigned stIn[WINB];      // 10.25 KB
    __shared__ int stOut[WINB];          // 10.25 KB
    __shared__ int lcnt[CB], lofs[CB], lcur[CB];
    __shared__ int wsum[2];
    __shared__ int acur;
    int B = blockIdx.x, t = threadIdx.x;
    int nvalid = min(CB, N_NODES - B * CB);
    int obase = B * WINB;

    if (t < CB) {
        lcnt[t] = (t < nvalid) ? 1 : 0;   // self-loop pre-count
        lcur[t] = 1;                      // slot 0 = self-loop
    }
    if (t == 0) acur = 0;
    __syncthreads();

    // single pass: append records to stIn + histogram.
    // ofsT reads are coalesced (unit-stride across threads).
    for (int blk = t; blk < NPB; blk += 512) {
        int o0 = ofsT[(size_t)B       * NPB + blk];
        int o1 = ofsT[(size_t)(B + 1) * NPB + blk];
        int n = o1 - o0;
        if (n > 0) {
            int p = atomicAdd(&acur, n);
            const unsigned* pp = pairs + (size_t)blk * TP + o0;
            for (int i = 0; i < n; ++i) {
                unsigned r = pp[i];
                stIn[p + i] = r;
                atomicAdd(&lcnt[r >> 17], 1);
            }
        }
    }
    __syncthreads();
    int m = acur;

    // exclusive scan over 128 bins (first 2 waves carry data)
    int v = (t < CB) ? lcnt[t] : 0;
    int ln = t & 63, wv = t >> 6;
    int sc = v;
#pragma unroll
    for (int off = 1; off < 64; off <<= 1) {
        int u = __shfl_up(sc, off, 64);
        if (ln >= off) sc += u;
    }
    if (ln == 63 && wv < 2) wsum[wv] = sc;
    __syncthreads();
    int wbase = (wv == 1) ? wsum[0] : 0;
    int ex = wbase + sc - v;
    if (t < CB) {
        lofs[t] = ex;
        int gi = B * CB + t;
        if (gi < N_NODES) {
            rbeg[gi] = obase + ex;
            rend[gi] = obase + ex + v;
            stOut[ex] = gi;               // self-loop record, slot 0
        }
    }
    __syncthreads();

    // scatter into final CSR order (LDS -> LDS)
    for (int k = t; k < m; k += 512) {
        unsigned p = stIn[k];
        int dl = p >> 17;
        int idx = atomicAdd(&lcur[dl], 1);
        stOut[lofs[dl] + idx] = (int)(p & 0x1FFFF);
    }
    __syncthreads();

    // coalesced dump
    int tot = m + nvalid;
    for (int i = t; i < tot; i += 512) ssrc[obase + i] = stOut[i];
}

// ---------------- layer 1 gather + softmax + ELU + fused node2 ----------
// HALF-WAVE (32 lanes) per dst: 2 dsts/wave -> 50K waves, per-dst
// epilogue wave-cost halved vs 64-lane layout. lane32 = (e = lane>>3 in
// 0..3 edge slots, h = lane&7 head). Single fully-predicated loop, 8
// edges/dst/iter (2 groups of 4). Divergence between the two halves is
// pure exec-masking.
__global__ void __launch_bounds__(256) k_gather1(
        const int* __restrict__ rbeg, const int* __restrict__ rend,
        const int* __restrict__ ssrc, const float4* __restrict__ xh4,
        const __half* __restrict__ as1h, const float* __restrict__ ad1,
        const float* __restrict__ b1, const float* __restrict__ W1,
        const float* __restrict__ W2,
        const float* __restrict__ a_src2, const float* __restrict__ a_dst2,
        float4* __restrict__ rec) {
    int gtid = blockIdx.x * blockDim.x + threadIdx.x;
    int d      = gtid >> 5;
    int lane32 = threadIdx.x & 31;
    if (d >= N_NODES) return;
    int e = lane32 >> 3;       // edge slot (0..3)
    int h = lane32 & 7;        // head

    int beg = rbeg[d], end = rend[d];
    float adv = ad1[d * 8 + h];                // pre-scaled by log2e
    float c0 = 0.f, c1 = 0.f, c2 = 0.f, c3 = 0.f, c4 = 0.f, den = 0.f;

    for (int k = beg; k < end; k += 8) {       // 2 predicated 4-edge groups
        int kA = k + e, kB = k + 4 + e;
        bool vA = kA < end, vB = kB < end;
        int sA = ssrc[vA ? kA : beg];
        int sB = ssrc[vB ? kB : beg];
        float eA = __half2float(as1h[sA * 8 + h]);
        float eB = __half2float(as1h[sB * 8 + h]);
        float4 xA = xh4[sA];                   // 8 halves: x0..x4,pad
        float4 xB = xh4[sB];
        float tA = eA + adv; tA = fmaxf(tA, NEG_SLOPE * tA);
        float tB = eB + adv; tB = fmaxf(tB, NEG_SLOPE * tB);
        float wA = vA ? __builtin_amdgcn_exp2f(tA) : 0.f;
        float wB = vB ? __builtin_amdgcn_exp2f(tB) : 0.f;
        float2 A01 = __half22float2(*(__half2*)&xA.x);
        float2 A23 = __half22float2(*(__half2*)&xA.y);
        float2 A4_ = __half22float2(*(__half2*)&xA.z);
        float2 B01 = __half22float2(*(__half2*)&xB.x);
        float2 B23 = __half22float2(*(__half2*)&xB.y);
        float2 B4_ = __half22float2(*(__half2*)&xB.z);
        c0 += wA * A01.x + wB * B01.x;
        c1 += wA * A01.y + wB * B01.y;
        c2 += wA * A23.x + wB * B23.x;
        c3 += wA * A23.y + wB * B23.y;
        c4 += wA * A4_.x + wB * B4_.x;
        den += wA + wB;
    }

    // reduce across the 4 edge slots (lane bits 3,4 — stays in half-wave)
#define REDH(x) x += __shfl_xor(x, 8, 64); x += __shfl_xor(x, 16, 64);
    REDH(c0) REDH(c1) REDH(c2) REDH(c3) REDH(c4) REDH(den)
#undef REDH

    float inv = 1.f / den;                     // den>0 (self-loop guarantees)
    float xs[5];
    xs[0] = c0 * inv; xs[1] = c1 * inv; xs[2] = c2 * inv;
    xs[3] = c3 * inv; xs[4] = c4 * inv;       // alpha-weighted mean x row

    // h = (sum alpha x) * W1 + b1  — this head's 8 channels, fp32
    float4 hA = ((const float4*)b1)[2 * h];
    float4 hB = ((const float4*)b1)[2 * h + 1];
#pragma unroll
    for (int c = 0; c < 5; ++c) {
        float xc = xs[c];
        float4 wA = *(const float4*)(W1 + c * 64 + 8 * h);
        float4 wB = *(const float4*)(W1 + c * 64 + 8 * h + 4);
        hA.x += xc * wA.x; hA.y += xc * wA.y; hA.z += xc * wA.z; hA.w += xc * wA.w;
        hB.x += xc * wB.x; hB.y += xc * wB.y; hB.z += xc * wB.z; hB.w += xc * wB.w;
    }
    float v0 = hA.x, v1 = hA.y, v2 = hA.z, v3 = hA.w;
    float v4 = hB.x, v5 = hB.y, v6 = hB.z, v7 = hB.w;
    v0 = (v0 > 0.f) ? v0 : (__expf(v0) - 1.f); // ELU
    v1 = (v1 > 0.f) ? v1 : (__expf(v1) - 1.f);
    v2 = (v2 > 0.f) ? v2 : (__expf(v2) - 1.f);
    v3 = (v3 > 0.f) ? v3 : (__expf(v3) - 1.f);
    v4 = (v4 > 0.f) ? v4 : (__expf(v4) - 1.f);
    v5 = (v5 > 0.f) ? v5 : (__expf(v5) - 1.f);
    v6 = (v6 > 0.f) ? v6 : (__expf(v6) - 1.f);
    v7 = (v7 > 0.f) ? v7 : (__expf(v7) - 1.f);

    // fused layer-2 transform: this lane's 8 channels (head h) x W2[64,2]
    const float4* w4 = (const float4*)(W2 + h * 16);
    float4 wq0 = w4[0], wq1 = w4[1], wq2 = w4[2], wq3 = w4[3];
    float h20 = v0 * wq0.x + v1 * wq0.z + v2 * wq1.x + v3 * wq1.z
              + v4 * wq2.x + v5 * wq2.z + v6 * wq3.x + v7 * wq3.z;
    float h21 = v0 * wq0.y + v1 * wq0.w + v2 * wq1.y + v3 * wq1.w
              + v4 * wq2.y + v5 * wq2.w + v6 * wq3.y + v7 * wq3.w;
    // reduce across the 8 heads (lane bits 0..2 — stays in half-wave)
    h20 += __shfl_xor(h20, 1, 64); h20 += __shfl_xor(h20, 2, 64); h20 += __shfl_xor(h20, 4, 64);
    h21 += __shfl_xor(h21, 1, 64); h21 += __shfl_xor(h21, 2, 64); h21 += __shfl_xor(h21, 4, 64);

    if (lane32 == 0) {
        float as2v = h20 * a_src2[0] + h21 * a_src2[1];
        float ad2v = h20 * a_dst2[0] + h21 * a_dst2[1];
        rec[d] = make_float4(h20, h21, as2v, ad2v);
    }
}

// ---------------- layer 2: per-dst gather + log_softmax -----------------
__global__ void k_gather2(const int* __restrict__ rbeg, const int* __restrict__ rend,
                          const int* __restrict__ ssrc, const float4* __restrict__ rec,
                          const float* __restrict__ b2, float* __restrict__ out) {
    int gtid = blockIdx.x * blockDim.x + threadIdx.x;
    int d    = gtid >> 4;
    int lane = gtid & 15;
    if (d >= N_NODES) return;

    int beg = rbeg[d], end = rend[d];
    float adv = rec[d].w;
    float n0 = 0.f, n1 = 0.f, den = 0.f;
    int k = beg + lane;
    for (; k + 16 < end; k += 32) {
        int s0 = ssrc[k], s1 = ssrc[k + 16];
        float4 r0 = rec[s0];
        float4 r1 = rec[s1];
        float t0 = r0.z + adv; t0 = fmaxf(t0, NEG_SLOPE * t0);
        float t1 = r1.z + adv; t1 = fmaxf(t1, NEG_SLOPE * t1);
        float w0 = __expf(t0), w1 = __expf(t1);
        n0 += w0 * r0.x + w1 * r1.x;
        n1 += w0 * r0.y + w1 * r1.y;
        den += w0 + w1;
    }
    if (k < end) {
        int s = ssrc[k];
        float4 r = rec[s];
        float t = r.z + adv; t = fmaxf(t, NEG_SLOPE * t);
        float w = __expf(t);
        n0 += w * r.x; n1 += w * r.y; den += w;
    }
#pragma unroll
    for (int off = 8; off; off >>= 1) {
        n0  += __shfl_xor(n0,  off, 16);
        n1  += __shfl_xor(n1,  off, 16);
        den += __shfl_xor(den, off, 16);
    }
    if (lane == 0) {
        float o0 = n0 / den + b2[0];
        float o1 = n1 / den + b2[1];
        float m  = fmaxf(o0, o1);
        float lse = m + __logf(__expf(o0 - m) + __expf(o1 - m));
        out[d * 2 + 0] = o0 - lse;
        out[d * 2 + 1] = o1 - lse;
    }
}

extern "C" void kernel_launch(void* const* d_in, const int* in_sizes, int n_in,
                              void* d_out, int out_size, void* d_ws, size_t ws_size,
                              hipStream_t stream) {
    const float* x      = (const float*)d_in[0];
    const int*   ei     = (const int*)d_in[1];     // [2, E] int32
    const float* W1     = (const float*)d_in[2];
    const float* a_src1 = (const float*)d_in[3];
    const float* a_dst1 = (const float*)d_in[4];
    const float* b1     = (const float*)d_in[5];
    const float* W2     = (const float*)d_in[6];
    const float* a_src2 = (const float*)d_in[7];
    const float* a_dst2 = (const float*)d_in[8];
    const float* b2     = (const float*)d_in[9];
    float* out = (float*)d_out;

    const int* src = ei;
    const int* dst = ei + N_EDGES;

    // ---- workspace layout (~26 MB), everything written before read:
    // no memset needed.
    int* ofsT   = (int*)d_ws;                                   // (NCB+1)*NPB (2.45 MB)
    int* rbeg   = ofsT + (size_t)(NCB + 1) * NPB;               // N
    int* rend   = rbeg + N_NODES;                               // N
    unsigned* pairs = (unsigned*)(rend + N_NODES);              // E (6.4 MB)
    int* ssrc   = (int*)(pairs + N_EDGES);                      // NCB*WINB (8 MB)
    uintptr_t pp = ((uintptr_t)(ssrc + (size_t)NCB * WINB) + 255) & ~(uintptr_t)255;
    float4*   rec  = (float4*)pp;                               // N float4
    float*    ad1  = (float*)(rec + N_NODES);                   // N*8 fp32
    __half*   as1h = (__half*)(ad1 + (size_t)N_NODES * 8);      // N*8 fp16
    __half*   xh   = as1h + (size_t)N_NODES * 8;                // N*8 fp16 (padded x rows)

    k_node1<<<(N_NODES * 8 + 255) / 256, 256, 0, stream>>>(x, W1, a_src1, a_dst1,
                                                           xh, as1h, ad1);
    k_part<<<NPB, 512, 0, stream>>>(src, dst, ofsT, pairs);
    k_csr<<<NCB, 512, 0, stream>>>(ofsT, pairs, rbeg, rend, ssrc);
    k_gather1<<<(N_NODES * 32 + 255) / 256, 256, 0, stream>>>(rbeg, rend, ssrc,
                                                              (const float4*)xh,
                                                              as1h, ad1, b1, W1, W2,
                                                              a_src2, a_dst2, rec);
    k_gather2<<<(N_NODES * 16 + 255) / 256, 256, 0, stream>>>(rbeg, rend, ssrc,
                                                              rec, b2, out);
}

// Round 6
// 162.051 us; speedup vs baseline: 1.2279x; 1.0754x over previous
//
#include <hip/hip_runtime.h>
#include <hip/hip_fp16.h>
#include <math.h>
#include <stdint.h>

#define N_NODES 100000
#define N_EDGES 1600000
#define N_TOT   (N_EDGES + N_NODES)   // edges + self-loops
#define NEG_SLOPE 0.2f
#define LOG2E 1.44269504088896340736f

#define CB     128                            // dst nodes per bucket
#define CBBITS 7
#define NCB    ((N_NODES + CB - 1) / CB)      // 782 buckets
#define TP     2048                           // edges per partition block
#define NPB    ((N_EDGES + TP - 1) / TP)      // 782 partition blocks
#define WINB   2560                           // fixed ssrc window per bucket (mean load 2174, +11 sigma)
#define NB_NODE1 ((N_NODES * 8 + 511) / 512)  // node1 blocks in fused kernel

typedef int nt_int4 __attribute__((ext_vector_type(4)));

// ---------------- fused: block-radix partition + node transform ---------
// Blocks [0, NPB): edge partition (LDS histogram + scan + scatter).
// Blocks [NPB, NPB+NB_NODE1): node transform (as/ad logits pre-scaled by
// log2e; padded fp16 x rows). The two halves are independent.
__global__ void __launch_bounds__(512) k_np(
        const int* __restrict__ src, const int* __restrict__ dst,
        int* __restrict__ ofsT, unsigned* __restrict__ pairs,
        const float* __restrict__ x, const float* __restrict__ W1,
        const float* __restrict__ a_src1, const float* __restrict__ a_dst1,
        __half* __restrict__ xh, __half* __restrict__ as1h,
        float* __restrict__ ad1) {
    __shared__ int lcnt[1024];           // bins (782 used), then cursors
    __shared__ int sm[512];
    __shared__ unsigned stage[TP];       // 8 KB
    int t = threadIdx.x;

    if (blockIdx.x >= NPB) {
        // ---------- node1 half ----------
        int gid  = (blockIdx.x - NPB) * 512 + t;
        int n    = gid >> 3;
        int head = gid & 7;
        if (n >= N_NODES) return;

        float xv[5];
#pragma unroll
        for (int k = 0; k < 5; ++k) xv[k] = x[n * 5 + k];

        float as = 0.f, ad = 0.f;
#pragma unroll
        for (int j = 0; j < 8; ++j) {
            int c = head * 8 + j;
            float acc = 0.f;
#pragma unroll
            for (int k = 0; k < 5; ++k) acc += xv[k] * W1[k * 64 + c];
            as += acc * a_src1[c];
            ad += acc * a_dst1[c];
        }
        as1h[n * 8 + head] = __float2half(as * LOG2E);
        ad1[n * 8 + head] = ad * LOG2E;

        if (head == 0) {                // padded fp16 x row: 8 halves = 16 B
            __half2 p0 = __halves2half2(__float2half(xv[0]), __float2half(xv[1]));
            __half2 p1 = __halves2half2(__float2half(xv[2]), __float2half(xv[3]));
            __half2 p2 = __halves2half2(__float2half(xv[4]), __float2half(0.f));
            __half2 p3 = __halves2half2(__float2half(0.f), __float2half(0.f));
            __half2* xp = (__half2*)&xh[(size_t)n * 8];
            xp[0] = p0; xp[1] = p1; xp[2] = p2; xp[3] = p3;
        }
        return;
    }

    // ---------- partition half ----------
    int blk = blockIdx.x;
    int base = blk * TP + t * 4;
    bool act = base < N_EDGES;           // tail block: exact multiple of 4
    int nE = min(TP, N_EDGES - blk * TP);

    lcnt[t] = 0; lcnt[t + 512] = 0;
    __syncthreads();

    nt_int4 s4, d4;
    if (act) {
        s4 = __builtin_nontemporal_load((const nt_int4*)(src + base));
        d4 = __builtin_nontemporal_load((const nt_int4*)(dst + base));
#pragma unroll
        for (int j = 0; j < 4; ++j) atomicAdd(&lcnt[d4[j] >> CBBITS], 1);
    }
    __syncthreads();

    // exclusive scan over 1024 bins, 2/thread
    int b0 = lcnt[t * 2], b1 = lcnt[t * 2 + 1];
    int local = b0 + b1;
    sm[t] = local;
    __syncthreads();
    for (int off = 1; off < 512; off <<= 1) {
        int u = (t >= off) ? sm[t - off] : 0;
        __syncthreads();
        sm[t] += u;
        __syncthreads();
    }
    int run = sm[t] - local;
    lcnt[t * 2] = run; lcnt[t * 2 + 1] = run + b0;
    if (t * 2     <= NCB) ofsT[(size_t)(t * 2)     * NPB + blk] = run;
    if (t * 2 + 1 <= NCB) ofsT[(size_t)(t * 2 + 1) * NPB + blk] = run + b0;
    __syncthreads();

    if (act) {
#pragma unroll
        for (int j = 0; j < 4; ++j) {
            int d = d4[j], s = s4[j];
            int bin = d >> CBBITS;
            int idx = atomicAdd(&lcnt[bin], 1);
            stage[idx] = ((unsigned)(d & (CB - 1)) << 17) | (unsigned)s;
        }
    }
    __syncthreads();
    for (int i = t; i < nE; i += 512)
        pairs[(size_t)blk * TP + i] = stage[i];      // coalesced dump
}

// ---------------- bucket-local CSR build, single-pass (782 x 512) -------
__global__ void __launch_bounds__(512) k_csr(
        const int* __restrict__ ofsT, const unsigned* __restrict__ pairs,
        int* __restrict__ rbeg, int* __restrict__ rend, int* __restrict__ ssrc) {
    __shared__ unsigned stIn[WINB];      // 10.25 KB
    __shared__ int stOut[WINB];          // 10.25 KB
    __shared__ int lcnt[CB], lofs[CB], lcur[CB];
    __shared__ int wsum[2];
    __shared__ int acur;
    int B = blockIdx.x, t = threadIdx.x;
    int nvalid = min(CB, N_NODES - B * CB);
    int obase = B * WINB;

    if (t < CB) {
        lcnt[t] = (t < nvalid) ? 1 : 0;   // self-loop pre-count
        lcur[t] = 1;                      // slot 0 = self-loop
    }
    if (t == 0) acur = 0;
    __syncthreads();

    // single pass: append records to stIn + histogram.
    // ofsT reads are coalesced (unit-stride across threads).
    for (int blk = t; blk < NPB; blk += 512) {
        int o0 = ofsT[(size_t)B       * NPB + blk];
        int o1 = ofsT[(size_t)(B + 1) * NPB + blk];
        int n = o1 - o0;
        if (n > 0) {
            int p = atomicAdd(&acur, n);
            const unsigned* pp = pairs + (size_t)blk * TP + o0;
            for (int i = 0; i < n; ++i) {
                unsigned r = pp[i];
                stIn[p + i] = r;
                atomicAdd(&lcnt[r >> 17], 1);
            }
        }
    }
    __syncthreads();
    int m = acur;

    // exclusive scan over 128 bins (first 2 waves carry data)
    int v = (t < CB) ? lcnt[t] : 0;
    int ln = t & 63, wv = t >> 6;
    int sc = v;
#pragma unroll
    for (int off = 1; off < 64; off <<= 1) {
        int u = __shfl_up(sc, off, 64);
        if (ln >= off) sc += u;
    }
    if (ln == 63 && wv < 2) wsum[wv] = sc;
    __syncthreads();
    int wbase = (wv == 1) ? wsum[0] : 0;
    int ex = wbase + sc - v;
    if (t < CB) {
        lofs[t] = ex;
        int gi = B * CB + t;
        if (gi < N_NODES) {
            rbeg[gi] = obase + ex;
            rend[gi] = obase + ex + v;
            stOut[ex] = gi;               // self-loop record, slot 0
        }
    }
    __syncthreads();

    // scatter into final CSR order (LDS -> LDS)
    for (int k = t; k < m; k += 512) {
        unsigned p = stIn[k];
        int dl = p >> 17;
        int idx = atomicAdd(&lcur[dl], 1);
        stOut[lofs[dl] + idx] = (int)(p & 0x1FFFF);
    }
    __syncthreads();

    // coalesced dump
    int tot = m + nvalid;
    for (int i = t; i < tot; i += 512) ssrc[obase + i] = stOut[i];
}

// ---------------- layer 1 gather + softmax (loop only) ------------------
// HALF-WAVE (32 lanes) per dst, lane32 = (e = lane>>3 edge slot 0..3,
// h = lane&7 head). The per-dst epilogue (W1 projection, ELU, W2) is
// EXCISED to k_rec: this kernel stores only the normalized per-(dst,head)
// alpha-weighted x-sums (5 floats, padded to 6) — gather work only.
__global__ void __launch_bounds__(256) k_gather1(
        const int* __restrict__ rbeg, const int* __restrict__ rend,
        const int* __restrict__ ssrc, const float4* __restrict__ xh4,
        const __half* __restrict__ as1h, const float* __restrict__ ad1,
        float* __restrict__ xsbuf) {
    int gtid = blockIdx.x * blockDim.x + threadIdx.x;
    int d      = gtid >> 5;
    int lane32 = threadIdx.x & 31;
    if (d >= N_NODES) return;
    int e = lane32 >> 3;       // edge slot (0..3)
    int h = lane32 & 7;        // head

    int beg = rbeg[d], end = rend[d];
    float adv = ad1[d * 8 + h];                // pre-scaled by log2e
    float c0 = 0.f, c1 = 0.f, c2 = 0.f, c3 = 0.f, c4 = 0.f, den = 0.f;

    for (int k = beg; k < end; k += 8) {       // 2 predicated 4-edge groups
        int kA = k + e, kB = k + 4 + e;
        bool vA = kA < end, vB = kB < end;
        int sA = ssrc[vA ? kA : beg];
        int sB = ssrc[vB ? kB : beg];
        float eA = __half2float(as1h[sA * 8 + h]);
        float eB = __half2float(as1h[sB * 8 + h]);
        float4 xA = xh4[sA];                   // 8 halves: x0..x4,pad
        float4 xB = xh4[sB];
        float tA = eA + adv; tA = fmaxf(tA, NEG_SLOPE * tA);
        float tB = eB + adv; tB = fmaxf(tB, NEG_SLOPE * tB);
        float wA = vA ? __builtin_amdgcn_exp2f(tA) : 0.f;
        float wB = vB ? __builtin_amdgcn_exp2f(tB) : 0.f;
        float2 A01 = __half22float2(*(__half2*)&xA.x);
        float2 A23 = __half22float2(*(__half2*)&xA.y);
        float2 A4_ = __half22float2(*(__half2*)&xA.z);
        float2 B01 = __half22float2(*(__half2*)&xB.x);
        float2 B23 = __half22float2(*(__half2*)&xB.y);
        float2 B4_ = __half22float2(*(__half2*)&xB.z);
        c0 += wA * A01.x + wB * B01.x;
        c1 += wA * A01.y + wB * B01.y;
        c2 += wA * A23.x + wB * B23.x;
        c3 += wA * A23.y + wB * B23.y;
        c4 += wA * A4_.x + wB * B4_.x;
        den += wA + wB;
    }

    // reduce across the 4 edge slots (lane bits 3,4 — stays in half-wave)
#define REDH(x) x += __shfl_xor(x, 8, 64); x += __shfl_xor(x, 16, 64);
    REDH(c0) REDH(c1) REDH(c2) REDH(c3) REDH(c4) REDH(den)
#undef REDH

    if (e == 0) {                              // one lane per (dst, head)
        float inv = 1.f / den;                 // den>0 (self-loop guarantees)
        float* xp = xsbuf + ((size_t)d * 8 + h) * 6;   // 24B stride, 8B-aligned
        *(float2*)(xp + 0) = make_float2(c0 * inv, c1 * inv);
        *(float2*)(xp + 2) = make_float2(c2 * inv, c3 * inv);
        *(float2*)(xp + 4) = make_float2(c4 * inv, 0.f);
    }
}

// ---------------- per-dst epilogue: W1 + ELU + W2 + logits --------------
// 64 lanes = 8 dsts x 8 heads. Each lane: its (dst,head) xs row ->
// 8 channels of h1 -> ELU -> partial W2 dot; reduce over heads (xor
// 1,2,4); lane h==0 writes rec[d] = (h20, h21, as2, ad2).
__global__ void __launch_bounds__(256) k_rec(
        const float* __restrict__ xsbuf, const float* __restrict__ b1,
        const float* __restrict__ W1, const float* __restrict__ W2,
        const float* __restrict__ a_src2, const float* __restrict__ a_dst2,
        float4* __restrict__ rec) {
    int gtid = blockIdx.x * blockDim.x + threadIdx.x;
    int d = gtid >> 3;
    int h = gtid & 7;
    if (d >= N_NODES) return;

    const float* xp = xsbuf + ((size_t)d * 8 + h) * 6;
    float2 p0 = *(const float2*)(xp + 0);
    float2 p1 = *(const float2*)(xp + 2);
    float2 p2 = *(const float2*)(xp + 4);
    float xs[5] = { p0.x, p0.y, p1.x, p1.y, p2.x };

    // h = xs * W1 + b1 — this head's 8 channels, fp32
    float4 hA = ((const float4*)b1)[2 * h];
    float4 hB = ((const float4*)b1)[2 * h + 1];
#pragma unroll
    for (int c = 0; c < 5; ++c) {
        float xc = xs[c];
        float4 wA = *(const float4*)(W1 + c * 64 + 8 * h);
        float4 wB = *(const float4*)(W1 + c * 64 + 8 * h + 4);
        hA.x += xc * wA.x; hA.y += xc * wA.y; hA.z += xc * wA.z; hA.w += xc * wA.w;
        hB.x += xc * wB.x; hB.y += xc * wB.y; hB.z += xc * wB.z; hB.w += xc * wB.w;
    }
    float v0 = hA.x, v1 = hA.y, v2 = hA.z, v3 = hA.w;
    float v4 = hB.x, v5 = hB.y, v6 = hB.z, v7 = hB.w;
    v0 = (v0 > 0.f) ? v0 : (__expf(v0) - 1.f); // ELU
    v1 = (v1 > 0.f) ? v1 : (__expf(v1) - 1.f);
    v2 = (v2 > 0.f) ? v2 : (__expf(v2) - 1.f);
    v3 = (v3 > 0.f) ? v3 : (__expf(v3) - 1.f);
    v4 = (v4 > 0.f) ? v4 : (__expf(v4) - 1.f);
    v5 = (v5 > 0.f) ? v5 : (__expf(v5) - 1.f);
    v6 = (v6 > 0.f) ? v6 : (__expf(v6) - 1.f);
    v7 = (v7 > 0.f) ? v7 : (__expf(v7) - 1.f);

    // fused layer-2 transform: this lane's 8 channels (head h) x W2[64,2]
    const float4* w4 = (const float4*)(W2 + h * 16);
    float4 wq0 = w4[0], wq1 = w4[1], wq2 = w4[2], wq3 = w4[3];
    float h20 = v0 * wq0.x + v1 * wq0.z + v2 * wq1.x + v3 * wq1.z
              + v4 * wq2.x + v5 * wq2.z + v6 * wq3.x + v7 * wq3.z;
    float h21 = v0 * wq0.y + v1 * wq0.w + v2 * wq1.y + v3 * wq1.w
              + v4 * wq2.y + v5 * wq2.w + v6 * wq3.y + v7 * wq3.w;
    // reduce across the 8 heads (lane bits 0..2)
    h20 += __shfl_xor(h20, 1, 64); h20 += __shfl_xor(h20, 2, 64); h20 += __shfl_xor(h20, 4, 64);
    h21 += __shfl_xor(h21, 1, 64); h21 += __shfl_xor(h21, 2, 64); h21 += __shfl_xor(h21, 4, 64);

    if (h == 0) {
        float as2v = h20 * a_src2[0] + h21 * a_src2[1];
        float ad2v = h20 * a_dst2[0] + h21 * a_dst2[1];
        rec[d] = make_float4(h20, h21, as2v, ad2v);
    }
}

// ---------------- layer 2: per-dst gather + log_softmax -----------------
__global__ void k_gather2(const int* __restrict__ rbeg, const int* __restrict__ rend,
                          const int* __restrict__ ssrc, const float4* __restrict__ rec,
                          const float* __restrict__ b2, float* __restrict__ out) {
    int gtid = blockIdx.x * blockDim.x + threadIdx.x;
    int d    = gtid >> 4;
    int lane = gtid & 15;
    if (d >= N_NODES) return;

    int beg = rbeg[d], end = rend[d];
    float adv = rec[d].w;
    float n0 = 0.f, n1 = 0.f, den = 0.f;
    int k = beg + lane;
    for (; k + 16 < end; k += 32) {
        int s0 = ssrc[k], s1 = ssrc[k + 16];
        float4 r0 = rec[s0];
        float4 r1 = rec[s1];
        float t0 = r0.z + adv; t0 = fmaxf(t0, NEG_SLOPE * t0);
        float t1 = r1.z + adv; t1 = fmaxf(t1, NEG_SLOPE * t1);
        float w0 = __expf(t0), w1 = __expf(t1);
        n0 += w0 * r0.x + w1 * r1.x;
        n1 += w0 * r0.y + w1 * r1.y;
        den += w0 + w1;
    }
    if (k < end) {
        int s = ssrc[k];
        float4 r = rec[s];
        float t = r.z + adv; t = fmaxf(t, NEG_SLOPE * t);
        float w = __expf(t);
        n0 += w * r.x; n1 += w * r.y; den += w;
    }
#pragma unroll
    for (int off = 8; off; off >>= 1) {
        n0  += __shfl_xor(n0,  off, 16);
        n1  += __shfl_xor(n1,  off, 16);
        den += __shfl_xor(den, off, 16);
    }
    if (lane == 0) {
        float o0 = n0 / den + b2[0];
        float o1 = n1 / den + b2[1];
        float m  = fmaxf(o0, o1);
        float lse = m + __logf(__expf(o0 - m) + __expf(o1 - m));
        out[d * 2 + 0] = o0 - lse;
        out[d * 2 + 1] = o1 - lse;
    }
}

extern "C" void kernel_launch(void* const* d_in, const int* in_sizes, int n_in,
                              void* d_out, int out_size, void* d_ws, size_t ws_size,
                              hipStream_t stream) {
    const float* x      = (const float*)d_in[0];
    const int*   ei     = (const int*)d_in[1];     // [2, E] int32
    const float* W1     = (const float*)d_in[2];
    const float* a_src1 = (const float*)d_in[3];
    const float* a_dst1 = (const float*)d_in[4];
    const float* b1     = (const float*)d_in[5];
    const float* W2     = (const float*)d_in[6];
    const float* a_src2 = (const float*)d_in[7];
    const float* a_dst2 = (const float*)d_in[8];
    const float* b2     = (const float*)d_in[9];
    float* out = (float*)d_out;

    const int* src = ei;
    const int* dst = ei + N_EDGES;

    // ---- workspace layout (~36 MB). REGION holds ofsT+pairs during
    // partition/CSR, then is REUSED as xsbuf (19.2 MB) by gather1/rec —
    // ofsT/pairs are dead after k_csr. Everything written before read.
    int* rbeg   = (int*)d_ws;                                   // N
    int* rend   = rbeg + N_NODES;                               // N
    int* ssrc   = rend + N_NODES;                               // NCB*WINB (8 MB)
    uintptr_t pp = ((uintptr_t)(ssrc + (size_t)NCB * WINB) + 255) & ~(uintptr_t)255;
    float4*   rec  = (float4*)pp;                               // N float4 (1.6 MB)
    float*    ad1  = (float*)(rec + N_NODES);                   // N*8 fp32 (3.2 MB)
    __half*   as1h = (__half*)(ad1 + (size_t)N_NODES * 8);      // N*8 fp16 (1.6 MB)
    __half*   xh   = as1h + (size_t)N_NODES * 8;                // N*8 fp16 (1.6 MB)
    uintptr_t rg = ((uintptr_t)(xh + (size_t)N_NODES * 8) + 255) & ~(uintptr_t)255;
    int*      ofsT  = (int*)rg;                                 // (NCB+1)*NPB (2.45 MB)
    unsigned* pairs = (unsigned*)(ofsT + (size_t)(NCB + 1) * NPB); // E (6.4 MB)
    float*    xsbuf = (float*)rg;                               // N*8*6 fp32 (19.2 MB, overlays ofsT+pairs)

    k_np<<<NPB + NB_NODE1, 512, 0, stream>>>(src, dst, ofsT, pairs,
                                             x, W1, a_src1, a_dst1,
                                             xh, as1h, ad1);
    k_csr<<<NCB, 512, 0, stream>>>(ofsT, pairs, rbeg, rend, ssrc);
    k_gather1<<<(N_NODES * 32 + 255) / 256, 256, 0, stream>>>(rbeg, rend, ssrc,
                                                              (const float4*)xh,
                                                              as1h, ad1, xsbuf);
    k_rec<<<(N_NODES * 8 + 255) / 256, 256, 0, stream>>>(xsbuf, b1, W1, W2,
                                                         a_src2, a_dst2, rec);
    k_gather2<<<(N_NODES * 16 + 255) / 256, 256, 0, stream>>>(rbeg, rend, ssrc,
                                                              rec, b2, out);
}